// Round 1
// baseline (272.058 us; speedup 1.0000x reference)
//
#include <hip/hip_runtime.h>

typedef __bf16 bf16;
typedef __bf16 bf16x4 __attribute__((ext_vector_type(4)));
typedef __bf16 bf16x8 __attribute__((ext_vector_type(8)));
typedef float f32x4 __attribute__((ext_vector_type(4)));
typedef short short4v __attribute__((ext_vector_type(4)));

#define TT_ 2048
#define CC_ 1024
#define HH_ 64

// scale * 1/ln(2): softmax via exp2, no max subtraction (|s|<~3, fp32-safe)
#define SCALE2 0.045084221f

// 16x16x16 bf16 MFMA (K=16): A-fragment k = 4*quad + j, which exactly matches
// the C-layout of a swapped QK^T (keys at quad*4+r) -> P feeds PV with zero
// cross-lane movement.
static __device__ __forceinline__ f32x4 mfma16x16x16(bf16x4 a, bf16x4 b, f32x4 c) {
#if __has_builtin(__builtin_amdgcn_mfma_f32_16x16x16_bf16)
    return __builtin_amdgcn_mfma_f32_16x16x16_bf16(a, b, c, 0, 0, 0);
#elif __has_builtin(__builtin_amdgcn_mfma_f32_16x16x16bf16_1k)
    return __builtin_amdgcn_mfma_f32_16x16x16bf16_1k(__builtin_bit_cast(short4v, a),
                                                     __builtin_bit_cast(short4v, b),
                                                     c, 0, 0, 0);
#else
    f32x4 d;
    asm("v_mfma_f32_16x16x16_bf16 %0, %1, %2, %3" : "=v"(d) : "v"(a), "v"(b), "v"(c));
    return d;
#endif
}

// ---------------- prep: Wt[m][n][k] = W_m[k][n], fp32 -> bf16, LDS transpose --
__global__ __launch_bounds__(256) void prep_w(const float* __restrict__ Wq,
                                              const float* __restrict__ Wk,
                                              const float* __restrict__ Wv,
                                              bf16* __restrict__ Wt) {
    __shared__ bf16 Ls[64 * 65];
    const int m  = blockIdx.x >> 4;
    const int k0 = (blockIdx.x & 15) * 64;
    const float* W = (m == 0) ? Wq : (m == 1) ? Wk : Wv;
    const int tid = threadIdx.x;
    #pragma unroll
    for (int j = 0; j < 4; ++j) {
        int idx = tid + 256 * j;
        int r   = idx >> 4;
        int c4  = (idx & 15) * 4;
        float4 w = *(const float4*)&W[(size_t)(k0 + r) * HH_ + c4];
        Ls[r * 65 + c4 + 0] = (bf16)w.x;
        Ls[r * 65 + c4 + 1] = (bf16)w.y;
        Ls[r * 65 + c4 + 2] = (bf16)w.z;
        Ls[r * 65 + c4 + 3] = (bf16)w.w;
    }
    __syncthreads();
    #pragma unroll
    for (int j = 0; j < 4; ++j) {
        int idx = tid + 256 * j;
        int n   = idx >> 4;
        int kc  = (idx & 15) * 4;
        bf16x4 v;
        #pragma unroll
        for (int i = 0; i < 4; ++i) v[i] = Ls[(kc + i) * 65 + n];
        *(bf16x4*)&Wt[m * 65536 + n * 1024 + k0 + kc] = v;
    }
}

// ---------------- fused QKV projection, double-buffered; V written transposed -
__global__ __launch_bounds__(256) void qkv_kernel(const float* __restrict__ x,
                                                  const bf16* __restrict__ Wt,
                                                  bf16* __restrict__ qb,
                                                  bf16* __restrict__ kb,
                                                  bf16* __restrict__ vt) {
    __shared__ __align__(16) bf16 Xs[2][64 * 72];
    const int tid  = threadIdx.x;
    const int wave = tid >> 6;
    const int lane = tid & 15;
    const int quad = (tid & 63) >> 4;
    const int m0   = blockIdx.x * 64;

    f32x4 acc[4][3];
    #pragma unroll
    for (int i = 0; i < 4; ++i)
        #pragma unroll
        for (int j = 0; j < 3; ++j) acc[i][j] = f32x4{0.f, 0.f, 0.f, 0.f};

    const int srow = tid >> 4;
    const int scol = (tid & 15) * 4;

    float4 xr[4];
    #pragma unroll
    for (int rr = 0; rr < 4; ++rr)
        xr[rr] = *(const float4*)&x[(size_t)(m0 + srow + rr * 16) * CC_ + scol];
    #pragma unroll
    for (int rr = 0; rr < 4; ++rr) {
        bf16x4 bv = {(bf16)xr[rr].x, (bf16)xr[rr].y, (bf16)xr[rr].z, (bf16)xr[rr].w};
        *(bf16x4*)&Xs[0][(srow + rr * 16) * 72 + scol] = bv;
    }

    for (int kbi = 0; kbi < 16; ++kbi) {
        const int cur = kbi & 1;
        const int k0  = kbi * 64;
        __syncthreads();
        if (kbi < 15) {
            #pragma unroll
            for (int rr = 0; rr < 4; ++rr)
                xr[rr] = *(const float4*)&x[(size_t)(m0 + srow + rr * 16) * CC_ + k0 + 64 + scol];
        }
        bf16x8 bfr[2][3];
        #pragma unroll
        for (int step = 0; step < 2; ++step)
            #pragma unroll
            for (int ct = 0; ct < 3; ++ct)
                bfr[step][ct] = *(const bf16x8*)&Wt[(size_t)(wave * 48 + ct * 16 + lane) * 1024 + k0 + step * 32 + quad * 8];
        bf16x8 afr[2][4];
        #pragma unroll
        for (int step = 0; step < 2; ++step)
            #pragma unroll
            for (int rt = 0; rt < 4; ++rt)
                afr[step][rt] = *(const bf16x8*)&Xs[cur][(rt * 16 + lane) * 72 + step * 32 + quad * 8];
        #pragma unroll
        for (int step = 0; step < 2; ++step)
            #pragma unroll
            for (int ct = 0; ct < 3; ++ct)
                #pragma unroll
                for (int rt = 0; rt < 4; ++rt)
                    acc[rt][ct] = __builtin_amdgcn_mfma_f32_16x16x32_bf16(afr[step][rt], bfr[step][ct], acc[rt][ct], 0, 0, 0);
        if (kbi < 15) {
            #pragma unroll
            for (int rr = 0; rr < 4; ++rr) {
                bf16x4 bv = {(bf16)xr[rr].x, (bf16)xr[rr].y, (bf16)xr[rr].z, (bf16)xr[rr].w};
                *(bf16x4*)&Xs[cur ^ 1][(srow + rr * 16) * 72 + scol] = bv;
            }
        }
    }

    // epilogue: C/D layout col=lane, row=quad*4+r
    const int bb = m0 >> 11;
    const int t0 = m0 & 2047;
    __syncthreads();
    #pragma unroll
    for (int ct = 0; ct < 3; ++ct) {
        int c0 = wave * 48 + ct * 16;
        if (c0 < 128) {
            bf16* outp = (c0 < 64) ? qb : kb;
            int h = (c0 & 63) + lane;
            #pragma unroll
            for (int rt = 0; rt < 4; ++rt)
                #pragma unroll
                for (int r = 0; r < 4; ++r)
                    outp[(size_t)(m0 + rt * 16 + quad * 4 + r) * HH_ + h] = (bf16)acc[rt][ct][r];
        } else {
            int h = (c0 - 128) + lane;
            #pragma unroll
            for (int rt = 0; rt < 4; ++rt)
                #pragma unroll
                for (int r = 0; r < 4; ++r)
                    Xs[0][(rt * 16 + quad * 4 + r) * 72 + h] = (bf16)acc[rt][ct][r];
        }
    }
    __syncthreads();
    {
        int h  = tid >> 2;
        int tc = (tid & 3) * 16;
        bf16x8 v0, v1;
        #pragma unroll
        for (int i = 0; i < 8; ++i) v0[i] = Xs[0][(tc + i) * 72 + h];
        #pragma unroll
        for (int i = 0; i < 8; ++i) v1[i] = Xs[0][(tc + 8 + i) * 72 + h];
        bf16* dst = &vt[(size_t)bb * HH_ * TT_ + (size_t)h * TT_ + t0 + tc];
        *(bf16x8*)dst = v0;
        *(bf16x8*)(dst + 8) = v1;
    }
}

// ---------------- flash attention, split-K (flash-decoding) ------------------
// grid (80, 16): idx -> (seg, qi); each block: <=4 chunks of 128 keys.
// Swapped QK^T: sfr = mfma(K_frag, Q_frag) = S^T tile. Each lane owns one
// q-row (q = lane&15) with keys at quad*4+r -- exactly the A-fragment layout
// of mfma_f32_16x16x16_bf16, so P feeds PV with no LDS round-trip.
// K fragments come straight from L2 (no staging); V is LDS double-buffered
// with split staging (loads issued early, ds_write after compute), ONE
// barrier per chunk. LDS 34.8 KB -> 4 blocks/CU.
__global__ __launch_bounds__(256, 4) void attn_kernel(const bf16* __restrict__ qb,
                                                      const bf16* __restrict__ kb,
                                                      const bf16* __restrict__ vt,
                                                      bf16* __restrict__ PO,
                                                      float* __restrict__ PL) {
    __shared__ __align__(16) bf16 Vs[2][64 * 136];   // V^T chunk: [h][s], dbuf

    const int tid  = threadIdx.x;
    const int wave = tid >> 6;
    const int lane = tid & 15;
    const int quad = (tid & 63) >> 4;
    const int idx = blockIdx.x;
    const int bb  = blockIdx.y;
    int seg, qi;
    if (idx < 32)      { seg = 0; qi = idx; }
    else if (idx < 56) { seg = 1; qi = idx - 24; }
    else if (idx < 72) { seg = 2; qi = idx - 40; }
    else               { seg = 3; qi = idx - 48; }
    const int q0    = qi * 64;
    const int nch   = (seg < (qi >> 3)) ? 4 : (((qi & 7) + 2) >> 1);
    const int diagc = (seg == (qi >> 3)) ? nch - 1 : -1;
    const int s00   = seg * 512;

    const int qrow  = q0 + wave * 16;
    const int qg    = qrow + lane;        // this lane's q row
    const int qmaxw = qrow + 15;          // max q row in this wave

    // Q fragment (B operand): lane -> q col, quad*8 -> h
    bf16x8 aq[2];
    #pragma unroll
    for (int step = 0; step < 2; ++step)
        aq[step] = *(const bf16x8*)&qb[(size_t)(bb * TT_ + qg) * HH_ + step * 32 + quad * 8];

    // K fragment base (A operand): lane -> key row, quad*8 -> h
    const bf16* kbase = kb + (size_t)(bb * TT_ + s00 + lane) * HH_ + quad * 8;

    // V staging: thread loads rows h0+16j, 8 keys at c8
    const int h0 = tid >> 4;
    const int c8 = (tid & 15) * 8;
    const bf16* vsrc = vt + (size_t)bb * HH_ * TT_ + (size_t)h0 * TT_ + c8;

    bf16x8 vr[4];
    #pragma unroll
    for (int j = 0; j < 4; ++j) vr[j] = *(const bf16x8*)&vsrc[s00 + j * 16 * TT_];
    #pragma unroll
    for (int j = 0; j < 4; ++j) *(bf16x8*)&Vs[0][(h0 + 16 * j) * 136 + c8] = vr[j];
    __syncthreads();

    f32x4 o_acc[4];
    #pragma unroll
    for (int ht = 0; ht < 4; ++ht) o_acc[ht] = f32x4{0.f, 0.f, 0.f, 0.f};
    float lsum = 0.f;

    for (int c = 0; c < nch; ++c) {
        const int s0 = s00 + c * 128;
        const bf16* Vcur = &Vs[c & 1][0];
        const bool msk = (c == diagc);

        // issue next chunk's V loads early (hidden under QK^T+softmax+PV)
        if (c + 1 < nch) {
            #pragma unroll
            for (int j = 0; j < 4; ++j)
                vr[j] = *(const bf16x8*)&vsrc[s0 + 128 + j * 16 * TT_];
        }

        // QK^T (swapped): sfr[nt][r] = S[key = s0+nt*16+quad*4+r][q = qg]
        f32x4 sfr[8];
        #pragma unroll
        for (int nt = 0; nt < 8; ++nt) {
            if (!msk || (s0 + nt * 16 <= qmaxw)) {   // wave-uniform diag skip
                bf16x8 ak0 = *(const bf16x8*)&kbase[(c * 128 + nt * 16) * HH_];
                bf16x8 ak1 = *(const bf16x8*)&kbase[(c * 128 + nt * 16) * HH_ + 32];
                f32x4 s = f32x4{0.f, 0.f, 0.f, 0.f};
                s = __builtin_amdgcn_mfma_f32_16x16x32_bf16(ak0, aq[0], s, 0, 0, 0);
                s = __builtin_amdgcn_mfma_f32_16x16x32_bf16(ak1, aq[1], s, 0, 0, 0);
                sfr[nt] = s;
            }
        }

        // softmax (in-register, max-free) + PV via 16x16x16 MFMA
        #pragma unroll
        for (int nt = 0; nt < 8; ++nt) {
            if (!msk || (s0 + nt * 16 <= qmaxw)) {
                const int kb0 = s0 + nt * 16 + quad * 4;
                f32x4 s = sfr[nt];
                float e0 = __builtin_amdgcn_exp2f(s[0] * SCALE2);
                float e1 = __builtin_amdgcn_exp2f(s[1] * SCALE2);
                float e2 = __builtin_amdgcn_exp2f(s[2] * SCALE2);
                float e3 = __builtin_amdgcn_exp2f(s[3] * SCALE2);
                if (msk) {
                    if (kb0 + 0 > qg) e0 = 0.f;
                    if (kb0 + 1 > qg) e1 = 0.f;
                    if (kb0 + 2 > qg) e2 = 0.f;
                    if (kb0 + 3 > qg) e3 = 0.f;
                }
                lsum += (e0 + e1) + (e2 + e3);
                bf16x4 ap = {(bf16)e0, (bf16)e1, (bf16)e2, (bf16)e3};
                #pragma unroll
                for (int ht = 0; ht < 4; ++ht) {
                    bf16x4 bv = *(const bf16x4*)&Vcur[(ht * 16 + lane) * 136 + nt * 16 + quad * 4];
                    o_acc[ht] = mfma16x16x16(ap, bv, o_acc[ht]);
                }
            }
        }

        // write next chunk's V into the other buffer; one barrier per chunk
        if (c + 1 < nch) {
            #pragma unroll
            for (int j = 0; j < 4; ++j)
                *(bf16x8*)&Vs[(c + 1) & 1][(h0 + 16 * j) * 136 + c8] = vr[j];
            __syncthreads();
        }
    }

    // epilogue: write unnormalized partials (o_acc layout same as before:
    // row = wave*16 + quad*4 + r, col = ht*16 + lane)
    const size_t p = (size_t)bb * 80 + idx;
    #pragma unroll
    for (int ht = 0; ht < 4; ++ht)
        #pragma unroll
        for (int r = 0; r < 4; ++r)
            PO[p * 4096 + (size_t)(wave * 16 + quad * 4 + r) * 64 + ht * 16 + lane] = (bf16)o_acc[ht][r];

    // row-sum: lane owns q = lane&15 partials; reduce across quads
    float l = lsum;
    l += __shfl_xor(l, 16);
    l += __shfl_xor(l, 32);
    if (quad == 0) PL[p * 64 + wave * 16 + lane] = l;
}

// ---------------- combine: sum partials over segments, normalize -------------
__global__ __launch_bounds__(256) void combine_kernel(const bf16* __restrict__ PO,
                                                      const float* __restrict__ PL,
                                                      float* __restrict__ out) {
    const int qi = blockIdx.x, bb = blockIdx.y;
    const int tid = threadIdx.x;
    const int r  = tid >> 2;
    const int cb = (tid & 3) * 16;
    const int ns = (qi >> 3) + 1;
    const int off[4] = {0, 32, 56, 72};

    float acc[16];
    #pragma unroll
    for (int i = 0; i < 16; ++i) acc[i] = 0.f;
    float l = 0.f;
    for (int s = 0; s < ns; ++s) {
        const size_t p = (size_t)bb * 80 + off[s] + qi - 8 * s;
        l += PL[p * 64 + r];
        const bf16* po = &PO[p * 4096 + (size_t)r * 64 + cb];
        bf16x8 a0 = *(const bf16x8*)po;
        bf16x8 a1 = *(const bf16x8*)(po + 8);
        #pragma unroll
        for (int i = 0; i < 8; ++i) { acc[i] += (float)a0[i]; acc[8 + i] += (float)a1[i]; }
    }
    const float inv = 1.0f / l;
    float* dst = &out[(size_t)(bb * TT_ + qi * 64 + r) * HH_ + cb];
    #pragma unroll
    for (int v = 0; v < 4; ++v) {
        float4 o = {acc[v * 4] * inv, acc[v * 4 + 1] * inv, acc[v * 4 + 2] * inv, acc[v * 4 + 3] * inv};
        *(float4*)(dst + v * 4) = o;
    }
}

extern "C" void kernel_launch(void* const* d_in, const int* in_sizes, int n_in,
                              void* d_out, int out_size, void* d_ws, size_t ws_size,
                              hipStream_t stream) {
    const float* x  = (const float*)d_in[0];
    const float* Wq = (const float*)d_in[1];
    const float* Wk = (const float*)d_in[2];
    const float* Wv = (const float*)d_in[3];
    float* out = (float*)d_out;

    char* ws = (char*)d_ws;
    bf16*  qb = (bf16*)(ws);                       // 4 MiB
    bf16*  kb = (bf16*)(ws + 4194304);             // 4 MiB
    bf16*  vt = (bf16*)(ws + 8388608);             // 4 MiB  V^T [bb][h][t]
    bf16*  Wt = (bf16*)(ws + 12582912);            // 384 KiB
    bf16*  PO = (bf16*)(ws + 12976128);            // 1280*4096*2 = 10.5 MiB
    float* PL = (float*)(ws + 23461888);           // 1280*64*4 = 320 KiB

    prep_w<<<48, 256, 0, stream>>>(Wq, Wk, Wv, Wt);
    qkv_kernel<<<512, 256, 0, stream>>>(x, Wt, qb, kb, vt);
    attn_kernel<<<dim3(80, 16), 256, 0, stream>>>(qb, kb, vt, PO, PL);
    combine_kernel<<<dim3(32, 16), 256, 0, stream>>>(PO, PL, out);
}

// Round 2
// 244.482 us; speedup vs baseline: 1.1128x; 1.1128x over previous
//
#include <hip/hip_runtime.h>

typedef __bf16 bf16;
typedef __bf16 bf16x2 __attribute__((ext_vector_type(2)));
typedef __bf16 bf16x4 __attribute__((ext_vector_type(4)));
typedef __bf16 bf16x8 __attribute__((ext_vector_type(8)));
typedef float f32x4 __attribute__((ext_vector_type(4)));

#define TT_ 2048
#define CC_ 1024
#define HH_ 64

// scale * 1/ln(2): softmax via exp2, no max subtraction (|s|<~3, fp32-safe)
#define SCALE2 0.045084221f

static __device__ __forceinline__ unsigned pack_bf16(float a, float b) {
    union { bf16x2 h; unsigned u; } z;
    z.h = bf16x2{(bf16)a, (bf16)b};
    return z.u;
}
// v_permlane32_swap_b32: a' = [a.lo32 | b.lo32], b' = [a.hi32 | b.hi32]
static __device__ __forceinline__ void plswap32(unsigned &a, unsigned &b) {
    asm("v_permlane32_swap_b32 %0, %1" : "+v"(a), "+v"(b));
}
// v_permlane16_swap_b32: odd 16-rows of a swap with even 16-rows of b:
// a' = [a.r0, b.r0, a.r2, b.r2], b' = [a.r1, b.r1, a.r3, b.r3]
static __device__ __forceinline__ void plswap16(unsigned &a, unsigned &b) {
    asm("v_permlane16_swap_b32 %0, %1" : "+v"(a), "+v"(b));
}

// ---------------- prep: Wt[m][n][k] = W_m[k][n], fp32 -> bf16, LDS transpose --
__global__ __launch_bounds__(256) void prep_w(const float* __restrict__ Wq,
                                              const float* __restrict__ Wk,
                                              const float* __restrict__ Wv,
                                              bf16* __restrict__ Wt) {
    __shared__ bf16 Ls[64 * 65];
    const int m  = blockIdx.x >> 4;
    const int k0 = (blockIdx.x & 15) * 64;
    const float* W = (m == 0) ? Wq : (m == 1) ? Wk : Wv;
    const int tid = threadIdx.x;
    #pragma unroll
    for (int j = 0; j < 4; ++j) {
        int idx = tid + 256 * j;
        int r   = idx >> 4;
        int c4  = (idx & 15) * 4;
        float4 w = *(const float4*)&W[(size_t)(k0 + r) * HH_ + c4];
        Ls[r * 65 + c4 + 0] = (bf16)w.x;
        Ls[r * 65 + c4 + 1] = (bf16)w.y;
        Ls[r * 65 + c4 + 2] = (bf16)w.z;
        Ls[r * 65 + c4 + 3] = (bf16)w.w;
    }
    __syncthreads();
    #pragma unroll
    for (int j = 0; j < 4; ++j) {
        int idx = tid + 256 * j;
        int n   = idx >> 4;
        int kc  = (idx & 15) * 4;
        bf16x4 v;
        #pragma unroll
        for (int i = 0; i < 4; ++i) v[i] = Ls[(kc + i) * 65 + n];
        *(bf16x4*)&Wt[m * 65536 + n * 1024 + k0 + kc] = v;
    }
}

// ---------------- fused QKV projection, double-buffered; V written transposed -
__global__ __launch_bounds__(256) void qkv_kernel(const float* __restrict__ x,
                                                  const bf16* __restrict__ Wt,
                                                  bf16* __restrict__ qb,
                                                  bf16* __restrict__ kb,
                                                  bf16* __restrict__ vt) {
    __shared__ __align__(16) bf16 Xs[2][64 * 72];
    const int tid  = threadIdx.x;
    const int wave = tid >> 6;
    const int lane = tid & 15;
    const int quad = (tid & 63) >> 4;
    const int m0   = blockIdx.x * 64;

    f32x4 acc[4][3];
    #pragma unroll
    for (int i = 0; i < 4; ++i)
        #pragma unroll
        for (int j = 0; j < 3; ++j) acc[i][j] = f32x4{0.f, 0.f, 0.f, 0.f};

    const int srow = tid >> 4;
    const int scol = (tid & 15) * 4;

    float4 xr[4];
    #pragma unroll
    for (int rr = 0; rr < 4; ++rr)
        xr[rr] = *(const float4*)&x[(size_t)(m0 + srow + rr * 16) * CC_ + scol];
    #pragma unroll
    for (int rr = 0; rr < 4; ++rr) {
        bf16x4 bv = {(bf16)xr[rr].x, (bf16)xr[rr].y, (bf16)xr[rr].z, (bf16)xr[rr].w};
        *(bf16x4*)&Xs[0][(srow + rr * 16) * 72 + scol] = bv;
    }

    for (int kbi = 0; kbi < 16; ++kbi) {
        const int cur = kbi & 1;
        const int k0  = kbi * 64;
        __syncthreads();
        if (kbi < 15) {
            #pragma unroll
            for (int rr = 0; rr < 4; ++rr)
                xr[rr] = *(const float4*)&x[(size_t)(m0 + srow + rr * 16) * CC_ + k0 + 64 + scol];
        }
        bf16x8 bfr[2][3];
        #pragma unroll
        for (int step = 0; step < 2; ++step)
            #pragma unroll
            for (int ct = 0; ct < 3; ++ct)
                bfr[step][ct] = *(const bf16x8*)&Wt[(size_t)(wave * 48 + ct * 16 + lane) * 1024 + k0 + step * 32 + quad * 8];
        bf16x8 afr[2][4];
        #pragma unroll
        for (int step = 0; step < 2; ++step)
            #pragma unroll
            for (int rt = 0; rt < 4; ++rt)
                afr[step][rt] = *(const bf16x8*)&Xs[cur][(rt * 16 + lane) * 72 + step * 32 + quad * 8];
        #pragma unroll
        for (int step = 0; step < 2; ++step)
            #pragma unroll
            for (int ct = 0; ct < 3; ++ct)
                #pragma unroll
                for (int rt = 0; rt < 4; ++rt)
                    acc[rt][ct] = __builtin_amdgcn_mfma_f32_16x16x32_bf16(afr[step][rt], bfr[step][ct], acc[rt][ct], 0, 0, 0);
        if (kbi < 15) {
            #pragma unroll
            for (int rr = 0; rr < 4; ++rr) {
                bf16x4 bv = {(bf16)xr[rr].x, (bf16)xr[rr].y, (bf16)xr[rr].z, (bf16)xr[rr].w};
                *(bf16x4*)&Xs[cur ^ 1][(srow + rr * 16) * 72 + scol] = bv;
            }
        }
    }

    // epilogue: C/D layout col=lane, row=quad*4+r
    const int bb = m0 >> 11;
    const int t0 = m0 & 2047;
    __syncthreads();
    #pragma unroll
    for (int ct = 0; ct < 3; ++ct) {
        int c0 = wave * 48 + ct * 16;
        if (c0 < 128) {
            bf16* outp = (c0 < 64) ? qb : kb;
            int h = (c0 & 63) + lane;
            #pragma unroll
            for (int rt = 0; rt < 4; ++rt)
                #pragma unroll
                for (int r = 0; r < 4; ++r)
                    outp[(size_t)(m0 + rt * 16 + quad * 4 + r) * HH_ + h] = (bf16)acc[rt][ct][r];
        } else {
            int h = (c0 - 128) + lane;
            #pragma unroll
            for (int rt = 0; rt < 4; ++rt)
                #pragma unroll
                for (int r = 0; r < 4; ++r)
                    Xs[0][(rt * 16 + quad * 4 + r) * 72 + h] = (bf16)acc[rt][ct][r];
        }
    }
    __syncthreads();
    {
        int h  = tid >> 2;
        int tc = (tid & 3) * 16;
        bf16x8 v0, v1;
        #pragma unroll
        for (int i = 0; i < 8; ++i) v0[i] = Xs[0][(tc + i) * 72 + h];
        #pragma unroll
        for (int i = 0; i < 8; ++i) v1[i] = Xs[0][(tc + 8 + i) * 72 + h];
        bf16* dst = &vt[(size_t)bb * HH_ * TT_ + (size_t)h * TT_ + t0 + tc];
        *(bf16x8*)dst = v0;
        *(bf16x8*)(dst + 8) = v1;
    }
}

// ---------------- flash attention, split-K (flash-decoding) ------------------
// grid (80, 16): idx -> (seg, qi); each block: <=4 chunks of 128 keys.
// Round-0 skeleton (K+V staged in LDS, 2 barriers/chunk, all-x32 MFMA), but
// swapped QK^T: sfr = mfma(K_frag, Q_frag) -> lane owns q=lane&15, keys at
// quad*4+r. P is converted IN REGISTERS to the 16x16x32 A-fragment layout
// (lane in quad t holds keys t*8..t*8+7) via 4 packs + 2 permlane32_swap +
// 2 permlane16_swap per 32-key window -- Ps LDS round-trip deleted.
// LDS 53.2 -> 35.8 KB => 4 blocks/CU.
__global__ __launch_bounds__(256, 4) void attn_kernel(const bf16* __restrict__ qb,
                                                      const bf16* __restrict__ kb,
                                                      const bf16* __restrict__ vt,
                                                      bf16* __restrict__ PO,
                                                      float* __restrict__ PL) {
    __shared__ __align__(16) bf16 Ks[128 * 72];
    __shared__ __align__(16) bf16 Vs[64 * 136];

    const int tid  = threadIdx.x;
    const int wave = tid >> 6;
    const int lane = tid & 15;
    const int quad = (tid & 63) >> 4;
    const int idx = blockIdx.x;
    const int bb  = blockIdx.y;
    int seg, qi;
    if (idx < 32)      { seg = 0; qi = idx; }
    else if (idx < 56) { seg = 1; qi = idx - 24; }
    else if (idx < 72) { seg = 2; qi = idx - 40; }
    else               { seg = 3; qi = idx - 48; }
    const int q0    = qi * 64;
    const int nch   = (seg < (qi >> 3)) ? 4 : (((qi & 7) + 2) >> 1);
    const int diagc = (seg == (qi >> 3)) ? nch - 1 : -1;
    const int s00   = seg * 512;

    const int qrow  = q0 + wave * 16;
    const int qg    = qrow + lane;        // this lane's q row
    const int qmaxw = qrow + 15;          // max q row in this wave

    // Q fragment (B operand): lane -> q col, quad*8 -> h
    bf16x8 aq[2];
    #pragma unroll
    for (int step = 0; step < 2; ++step)
        aq[step] = *(const bf16x8*)&qb[(size_t)(bb * TT_ + qg) * HH_ + step * 32 + quad * 8];

    f32x4 o_acc[4];
    #pragma unroll
    for (int ht = 0; ht < 4; ++ht) o_acc[ht] = f32x4{0.f, 0.f, 0.f, 0.f};
    float lsum = 0.f;

    for (int c = 0; c < nch; ++c) {
        const int s0 = s00 + c * 128;
        __syncthreads();
        #pragma unroll
        for (int j = 0; j < 4; ++j) {       // K: 128 rows x 64 h
            int ch = tid + 256 * j;
            int row = ch >> 3, c8 = (ch & 7) * 8;
            *(bf16x8*)&Ks[row * 72 + c8] =
                *(const bf16x8*)&kb[(size_t)(bb * TT_ + s0 + row) * HH_ + c8];
        }
        #pragma unroll
        for (int j = 0; j < 4; ++j) {       // V^T: 64 rows(h) x 128 s
            int ch = tid + 256 * j;
            int h = ch >> 4, c8 = (ch & 15) * 8;
            *(bf16x8*)&Vs[h * 136 + c8] =
                *(const bf16x8*)&vt[(size_t)bb * HH_ * TT_ + (size_t)h * TT_ + s0 + c8];
        }
        __syncthreads();

        const bool msk = (c == diagc);
        #pragma unroll
        for (int w = 0; w < 4; ++w) {       // 4 windows of 32 keys
            if (msk && (s0 + w * 32 > qmaxw)) continue;       // wave-uniform
            const bool haveB = !msk || (s0 + w * 32 + 16 <= qmaxw);

            // QK^T (swapped): s[key=tile+quad*4+r][q=qg]
            f32x4 sA = {0.f, 0.f, 0.f, 0.f};
            f32x4 sB = {0.f, 0.f, 0.f, 0.f};
            {
                bf16x8 ak0 = *(const bf16x8*)&Ks[(w * 32 + lane) * 72 + quad * 8];
                bf16x8 ak1 = *(const bf16x8*)&Ks[(w * 32 + lane) * 72 + 32 + quad * 8];
                sA = __builtin_amdgcn_mfma_f32_16x16x32_bf16(ak0, aq[0], sA, 0, 0, 0);
                sA = __builtin_amdgcn_mfma_f32_16x16x32_bf16(ak1, aq[1], sA, 0, 0, 0);
            }
            if (haveB) {
                bf16x8 bk0 = *(const bf16x8*)&Ks[(w * 32 + 16 + lane) * 72 + quad * 8];
                bf16x8 bk1 = *(const bf16x8*)&Ks[(w * 32 + 16 + lane) * 72 + 32 + quad * 8];
                sB = __builtin_amdgcn_mfma_f32_16x16x32_bf16(bk0, aq[0], sB, 0, 0, 0);
                sB = __builtin_amdgcn_mfma_f32_16x16x32_bf16(bk1, aq[1], sB, 0, 0, 0);
            }

            // softmax (in-register, max-free)
            const int kA0 = s0 + w * 32 + quad * 4;
            float eA[4], eB[4];
            #pragma unroll
            for (int r = 0; r < 4; ++r) {
                float e = __builtin_amdgcn_exp2f(sA[r] * SCALE2);
                if (msk && (kA0 + r > qg)) e = 0.f;
                eA[r] = e;
            }
            if (haveB) {
                #pragma unroll
                for (int r = 0; r < 4; ++r) {
                    float e = __builtin_amdgcn_exp2f(sB[r] * SCALE2);
                    if (msk && (kA0 + 16 + r > qg)) e = 0.f;
                    eB[r] = e;
                }
            } else {
                #pragma unroll
                for (int r = 0; r < 4; ++r) eB[r] = 0.f;
            }
            lsum += ((eA[0] + eA[1]) + (eA[2] + eA[3])) +
                    ((eB[0] + eB[1]) + (eB[2] + eB[3]));

            // P: C-layout -> 16x16x32 A-layout, all in registers.
            // d0,d2 <- keys {0,1}/{4,5} per 8-key group; d1,d3 <- {2,3}/{6,7}
            unsigned d0 = pack_bf16(eA[0], eA[1]);
            unsigned d1 = pack_bf16(eA[2], eA[3]);
            unsigned d2 = pack_bf16(eB[0], eB[1]);
            unsigned d3 = pack_bf16(eB[2], eB[3]);
            plswap32(d0, d2);   // d0=[Aq0,Aq1,Bq0,Bq1] d2=[Aq2,Aq3,Bq2,Bq3]
            plswap16(d0, d2);   // d0=[Aq0,Aq2,Bq0,Bq2] d2=[Aq1,Aq3,Bq1,Bq3]
            plswap32(d1, d3);
            plswap16(d1, d3);
            union { unsigned u[4]; bf16x8 v; } apu;
            apu.u[0] = d0; apu.u[1] = d1; apu.u[2] = d2; apu.u[3] = d3;

            // PV: x32 MFMA straight from registers + Vs
            #pragma unroll
            for (int ht = 0; ht < 4; ++ht) {
                bf16x8 bv = *(const bf16x8*)&Vs[(ht * 16 + lane) * 136 + w * 32 + quad * 8];
                o_acc[ht] = __builtin_amdgcn_mfma_f32_16x16x32_bf16(apu.v, bv, o_acc[ht], 0, 0, 0);
            }
        }
    }

    // epilogue: write unnormalized partials
    // o_acc layout: row = wave*16 + quad*4 + r (q), col = ht*16 + lane (h)
    const size_t p = (size_t)bb * 80 + idx;
    #pragma unroll
    for (int ht = 0; ht < 4; ++ht)
        #pragma unroll
        for (int r = 0; r < 4; ++r)
            PO[p * 4096 + (size_t)(wave * 16 + quad * 4 + r) * 64 + ht * 16 + lane] = (bf16)o_acc[ht][r];

    // row-sum: lane owns q = lane&15; reduce across the 4 quads
    float l = lsum;
    l += __shfl_xor(l, 16);
    l += __shfl_xor(l, 32);
    if (quad == 0) PL[p * 64 + wave * 16 + lane] = l;
}

// ---------------- combine: sum partials over segments, normalize -------------
__global__ __launch_bounds__(256) void combine_kernel(const bf16* __restrict__ PO,
                                                      const float* __restrict__ PL,
                                                      float* __restrict__ out) {
    const int qi = blockIdx.x, bb = blockIdx.y;
    const int tid = threadIdx.x;
    const int r  = tid >> 2;
    const int cb = (tid & 3) * 16;
    const int ns = (qi >> 3) + 1;
    const int off[4] = {0, 32, 56, 72};

    float acc[16];
    #pragma unroll
    for (int i = 0; i < 16; ++i) acc[i] = 0.f;
    float l = 0.f;
    for (int s = 0; s < ns; ++s) {
        const size_t p = (size_t)bb * 80 + off[s] + qi - 8 * s;
        l += PL[p * 64 + r];
        const bf16* po = &PO[p * 4096 + (size_t)r * 64 + cb];
        bf16x8 a0 = *(const bf16x8*)po;
        bf16x8 a1 = *(const bf16x8*)(po + 8);
        #pragma unroll
        for (int i = 0; i < 8; ++i) { acc[i] += (float)a0[i]; acc[8 + i] += (float)a1[i]; }
    }
    const float inv = 1.0f / l;
    float* dst = &out[(size_t)(bb * TT_ + qi * 64 + r) * HH_ + cb];
    #pragma unroll
    for (int v = 0; v < 4; ++v) {
        float4 o = {acc[v * 4] * inv, acc[v * 4 + 1] * inv, acc[v * 4 + 2] * inv, acc[v * 4 + 3] * inv};
        *(float4*)(dst + v * 4) = o;
    }
}

extern "C" void kernel_launch(void* const* d_in, const int* in_sizes, int n_in,
                              void* d_out, int out_size, void* d_ws, size_t ws_size,
                              hipStream_t stream) {
    const float* x  = (const float*)d_in[0];
    const float* Wq = (const float*)d_in[1];
    const float* Wk = (const float*)d_in[2];
    const float* Wv = (const float*)d_in[3];
    float* out = (float*)d_out;

    char* ws = (char*)d_ws;
    bf16*  qb = (bf16*)(ws);                       // 4 MiB
    bf16*  kb = (bf16*)(ws + 4194304);             // 4 MiB
    bf16*  vt = (bf16*)(ws + 8388608);             // 4 MiB  V^T [bb][h][t]
    bf16*  Wt = (bf16*)(ws + 12582912);            // 384 KiB
    bf16*  PO = (bf16*)(ws + 12976128);            // 1280*4096*2 = 10.5 MiB
    float* PL = (float*)(ws + 23461888);           // 1280*64*4 = 320 KiB

    prep_w<<<48, 256, 0, stream>>>(Wq, Wk, Wv, Wt);
    qkv_kernel<<<512, 256, 0, stream>>>(x, Wt, qb, kb, vt);
    attn_kernel<<<dim3(80, 16), 256, 0, stream>>>(qb, kb, vt, PO, PL);
    combine_kernel<<<dim3(32, 16), 256, 0, stream>>>(PO, PL, out);
}